// Round 1
// baseline (109.197 us; speedup 1.0000x reference)
//
#include <hip/hip_runtime.h>
#include <math.h>

#define EPS 1e-8f
#define LN_2PI 1.8378770664093453f

__device__ __forceinline__ float redmax32(float v) {
    #pragma unroll
    for (int off = 16; off >= 1; off >>= 1)
        v = fmaxf(v, __shfl_xor(v, off));
    return v;
}
__device__ __forceinline__ float redsum32(float v) {
    #pragma unroll
    for (int off = 16; off >= 1; off >>= 1)
        v += __shfl_xor(v, off);
    return v;
}

// One block per output position n (392 total), 256 threads.
// thread t: c = t&31 (output capsule), g = t>>5 (m-group 0..7), m = g + 8k, k<36.
__global__ __launch_bounds__(256)
void convcaps_em_kernel(const float* __restrict__ x,
                        const float* __restrict__ w,
                        const float* __restrict__ bu,
                        const float* __restrict__ ba,
                        float* __restrict__ out)
{
    // 9 source pixels (544 ch each) for this n: pose xv[m][16] + a_in[m]
    __shared__ __align__(16) float sbuf[9 * 544];
    // cross-g reduction scratch: stride 33 words -> conflict-free
    __shared__ float red[8][32][33];

    const int n = blockIdx.x;
    const int t = threadIdx.x;
    const int c = t & 31;
    const int g = t >> 5;

    // ---- stage the 9 pixels: cell = n*9 + s over (b,kh,kw,i,j)=(8,3,3,7,7),
    // src pixel = x[b][2i+kh][2j+kw][:], 544 floats = 136 float4 ----
    for (int idx = t; idx < 9 * 136; idx += 256) {
        const int s  = idx / 136;
        const int e4 = idx - s * 136;
        int cell = n * 9 + s;
        const int b  = cell / 441; cell -= b * 441;
        const int kh = cell / 147; cell -= kh * 147;
        const int kw = cell / 49;  cell -= kw * 49;
        const int i  = cell / 7;
        const int j  = cell - i * 7;
        const float4* src = reinterpret_cast<const float4*>(
            x + (size_t)(((b * 16 + 2 * i + kh) * 16) + 2 * j + kw) * 544);
        reinterpret_cast<float4*>(sbuf + s * 544)[e4] = src[e4];
    }
    __syncthreads();

    const float bu_c = bu[c];
    const float ba_c = ba[c];

    float mu[16], is2[16];
    #pragma unroll
    for (int p = 0; p < 16; ++p) { mu[p] = 0.0f; is2[p] = 0.0f; }
    float constC = 0.0f, a_out_c = 0.0f;

    #pragma unroll 1
    for (int it = 0; it < 3; ++it) {
        float pS0 = 0.0f, pS1[16], pS2[16];
        #pragma unroll
        for (int p = 0; p < 16; ++p) { pS1[p] = 0.0f; pS2[p] = 0.0f; }

        #pragma unroll 1
        for (int k = 0; k < 36; ++k) {
            const int m = g + (k << 3);
            // xv fragment (broadcast across the 32 c-lanes)
            const float* xvp = sbuf + (m >> 5) * 544 + (m & 31) * 16;
            float xa[16];
            #pragma unroll
            for (int q4 = 0; q4 < 4; ++q4) {
                float4 tmp = reinterpret_cast<const float4*>(xvp)[q4];
                xa[q4*4+0] = tmp.x; xa[q4*4+1] = tmp.y;
                xa[q4*4+2] = tmp.z; xa[q4*4+3] = tmp.w;
            }
            const float a_in_m = sbuf[(m >> 5) * 544 + 512 + (m & 31)];
            // W fragment: lane c reads consecutive 64B chunk -> coalesced, L2-hot
            const float* wp = w + (size_t)(m * 32 + c) * 16;
            float wf[16];
            #pragma unroll
            for (int q4 = 0; q4 < 4; ++q4) {
                float4 tmp = reinterpret_cast<const float4*>(wp)[q4];
                wf[q4*4+0] = tmp.x; wf[q4*4+1] = tmp.y;
                wf[q4*4+2] = tmp.z; wf[q4*4+3] = tmp.w;
            }
            // v[p][r] = sum_q xa[p][q] * wf[q][r]
            float v[16];
            #pragma unroll
            for (int p = 0; p < 4; ++p) {
                #pragma unroll
                for (int r = 0; r < 4; ++r) {
                    float acc = xa[p*4+0] * wf[r];
                    acc = fmaf(xa[p*4+1], wf[4 + r],  acc);
                    acc = fmaf(xa[p*4+2], wf[8 + r],  acc);
                    acc = fmaf(xa[p*4+3], wf[12 + r], acc);
                    v[p*4+r] = acc;
                }
            }
            // rho = normalized r * a_in (fused e-step of previous iteration)
            float rho;
            if (it == 0) {
                // r = 1/32 uniform: rho = (a/32) / (a + eps)
                rho = (a_in_m * 0.03125f) / (a_in_m + EPS);
            } else {
                float s = 0.0f;
                #pragma unroll
                for (int p = 0; p < 16; ++p) {
                    const float d = v[p] - mu[p];
                    s = fmaf(d * d, is2[p], s);
                }
                const float lap = constC - s;          // ln_ap
                const float mx = redmax32(lap);        // stable softmax over c
                const float e  = __expf(lap - mx);
                const float Z  = redsum32(e);
                const float ra = (e / Z) * a_in_m;     // r * a_in
                const float S  = redsum32(ra);         // sum_c (r*a_in)
                rho = ra / (S + EPS);
            }
            pS0 += rho;
            #pragma unroll
            for (int p = 0; p < 16; ++p) {
                pS1[p] = fmaf(rho, v[p], pS1[p]);
                pS2[p] = fmaf(rho * v[p], v[p], pS2[p]);
            }
        }

        // ---- reduce partials over the 8 g-groups ----
        red[g][c][0] = pS0;
        #pragma unroll
        for (int p = 0; p < 16; ++p) {
            red[g][c][1 + p]  = pS1[p];
            red[g][c][17 + p] = pS2[p];
        }
        __syncthreads();
        float S0 = 0.0f, S1[16], S2[16];
        #pragma unroll
        for (int p = 0; p < 16; ++p) { S1[p] = 0.0f; S2[p] = 0.0f; }
        #pragma unroll
        for (int kk = 0; kk < 8; ++kk) {
            S0 += red[kk][c][0];
            #pragma unroll
            for (int p = 0; p < 16; ++p) {
                S1[p] += red[kk][c][1 + p];
                S2[p] += red[kk][c][17 + p];
            }
        }
        __syncthreads();   // red reused next iteration

        // ---- m-step closure: mu, sigma^2, a_out ----
        const float inv = 1.0f / (S0 + EPS);
        float sumHalfLog = 0.0f;
        #pragma unroll
        for (int p = 0; p < 16; ++p) {
            const float m_ = S1[p] * inv;
            const float sg = (S2[p] - 2.0f * m_ * S1[p] + m_ * m_ * S0) * inv + EPS;
            mu[p]  = m_;
            is2[p] = 0.5f / sg;                  // 1/(2 sigma^2)
            sumHalfLog += 0.5f * __logf(sg);     // log(sqrt(sigma^2))
        }
        const float cost = (16.0f * bu_c + sumHalfLog) * S0;
        const float itc = (it == 0) ? 5.0e-4f : ((it == 1) ? 9.75e-4f : 1.42625e-3f);
        a_out_c = 1.0f / (1.0f + __expf(-(itc * (ba_c - cost))));
        // for next e-step: ln a_out - sum_p log(sqrt(sg)) - 16*0.5*ln(2pi)
        constC = __logf(a_out_c) - sumHalfLog - 8.0f * LN_2PI;
    }

    // ---- output: out[n*544 + c*16 + p] = mu, out[n*544 + 512 + c] = a_out ----
    if (g == 0) {
        float* po = out + (size_t)n * 544 + c * 16;
        #pragma unroll
        for (int p4 = 0; p4 < 4; ++p4) {
            reinterpret_cast<float4*>(po)[p4] =
                make_float4(mu[p4*4+0], mu[p4*4+1], mu[p4*4+2], mu[p4*4+3]);
        }
        out[(size_t)n * 544 + 512 + c] = a_out_c;
    }
}

extern "C" void kernel_launch(void* const* d_in, const int* in_sizes, int n_in,
                              void* d_out, int out_size, void* d_ws, size_t ws_size,
                              hipStream_t stream) {
    const float* x  = (const float*)d_in[0];   // (8,16,16,544) f32
    const float* w  = (const float*)d_in[1];   // (1,288,32,4,4) f32
    const float* bu = (const float*)d_in[2];   // (32,) f32
    const float* ba = (const float*)d_in[3];   // (32,) f32
    float* out = (float*)d_out;                // (8,7,7,544) f32
    convcaps_em_kernel<<<392, 256, 0, stream>>>(x, w, bu, ba, out);
}